// Round 1
// baseline (337.363 us; speedup 1.0000x reference)
//
#include <hip/hip_runtime.h>
#include <hip/hip_bf16.h>

#define DEVI __device__ __forceinline__

typedef __attribute__((ext_vector_type(8))) short short8;
typedef __attribute__((ext_vector_type(4))) float floatx4;

static constexpr int B_ = 2, T_ = 2048, C_ = 1024, H_ = 16, D_ = 64;

DEVI float bf2f(unsigned short u) {
    union { unsigned int i; float f; } v; v.i = ((unsigned int)u) << 16; return v.f;
}
DEVI unsigned short f2bf(float f) {
    union { float f; unsigned int i; } v; v.f = f;
    unsigned int x = v.i;
    return (unsigned short)((x + 0x7fffu + ((x >> 16) & 1u)) >> 16);
}

// ---------------- convert fp32 -> bf16, 8 elems/thread ----------------
__global__ __launch_bounds__(256) void k_cvt(const float* __restrict__ in,
                                             unsigned short* __restrict__ out, int n8) {
    int i = blockIdx.x * 256 + threadIdx.x;
    if (i >= n8) return;
    const float4* p = (const float4*)in + (size_t)i * 2;
    float4 a = p[0], b = p[1];
    union { unsigned short u[8]; short8 s; } r;
    r.u[0] = f2bf(a.x); r.u[1] = f2bf(a.y); r.u[2] = f2bf(a.z); r.u[3] = f2bf(a.w);
    r.u[4] = f2bf(b.x); r.u[5] = f2bf(b.y); r.u[6] = f2bf(b.z); r.u[7] = f2bf(b.w);
    *(short8*)&out[(size_t)i * 8] = r.s;
}

// ---------------- transpose+convert: in f32 (K x N) -> out bf16 (N x K) ----------------
__global__ __launch_bounds__(256) void k_tr(const float* __restrict__ in,
                                            unsigned short* __restrict__ out, int K, int N) {
    __shared__ float tile[64][65];
    int k0 = blockIdx.y * 64, n0 = blockIdx.x * 64;
    int tid = threadIdx.x;
#pragma unroll
    for (int r = 0; r < 4; r++) {
        int ci = tid + r * 256;
        int row = ci >> 4, c4 = (ci & 15) * 4;
        float4 v = *(const float4*)&in[(size_t)(k0 + row) * N + n0 + c4];
        tile[row][c4 + 0] = v.x; tile[row][c4 + 1] = v.y;
        tile[row][c4 + 2] = v.z; tile[row][c4 + 3] = v.w;
    }
    __syncthreads();
#pragma unroll
    for (int r = 0; r < 2; r++) {
        int ci = tid + r * 256;
        int row = ci >> 3, c8 = (ci & 7) * 8;
        union { unsigned short u[8]; short8 s; } o;
#pragma unroll
        for (int j = 0; j < 8; j++) o.u[j] = f2bf(tile[c8 + j][row]);
        *(short8*)&out[(size_t)(n0 + row) * K + k0 + c8] = o.s;
    }
}

// ---------------- discourse bias: (d_bias - mean) * w_disc ----------------
__global__ __launch_bounds__(256) void k_bias(const float* __restrict__ d_bias,
                                              const float* __restrict__ w_disc,
                                              float* __restrict__ bias) {
    int h = blockIdx.x, tid = threadIdx.x;
    __shared__ float red[256];
    float s = 0.f;
    for (int t = tid; t < T_; t += 256) s += d_bias[h * T_ + t];
    red[tid] = s;
    __syncthreads();
    for (int st = 128; st > 0; st >>= 1) {
        if (tid < st) red[tid] += red[tid + st];
        __syncthreads();
    }
    float mean = red[0] * (1.0f / T_);
    float wd = w_disc[h];
    for (int t = tid; t < T_; t += 256) bias[h * T_ + t] = (d_bias[h * T_ + t] - mean) * wd;
}

// ---------------- bf16 GEMM: C(MxN) = A(MxK) * Bt(NxK)^T ----------------
template <typename OUT>
__global__ __launch_bounds__(256) void k_gemm(const unsigned short* __restrict__ A,
                                              const unsigned short* __restrict__ Bt,
                                              OUT* __restrict__ C, int M, int N, int K) {
    __shared__ __align__(16) unsigned short As[128 * 32];
    __shared__ __align__(16) unsigned short Bs[128 * 32];
    int m0 = blockIdx.y * 128, n0 = blockIdx.x * 128;
    int tid = threadIdx.x, l = tid & 63, w = tid >> 6;
    int wm = (w >> 1) * 64, wn = (w & 1) * 64;
    int lm = l & 15, lq = l >> 4;
    floatx4 acc[4][4];
#pragma unroll
    for (int a = 0; a < 4; a++)
#pragma unroll
        for (int b = 0; b < 4; b++) acc[a][b] = {0.f, 0.f, 0.f, 0.f};

    for (int k0 = 0; k0 < K; k0 += 32) {
        __syncthreads();
#pragma unroll
        for (int r = 0; r < 2; r++) {
            int ci = tid + r * 256;
            int row = ci >> 2, off = (ci & 3) * 8;
            *(short8*)&As[row * 32 + off] = *(const short8*)&A[(size_t)(m0 + row) * K + k0 + off];
            *(short8*)&Bs[row * 32 + off] = *(const short8*)&Bt[(size_t)(n0 + row) * K + k0 + off];
        }
        __syncthreads();
        short8 af[4], bf[4];
#pragma unroll
        for (int t = 0; t < 4; t++) af[t] = *(short8*)&As[(wm + t * 16 + lm) * 32 + lq * 8];
#pragma unroll
        for (int t = 0; t < 4; t++) bf[t] = *(short8*)&Bs[(wn + t * 16 + lm) * 32 + lq * 8];
#pragma unroll
        for (int tm = 0; tm < 4; tm++)
#pragma unroll
            for (int tn = 0; tn < 4; tn++)
                acc[tm][tn] = __builtin_amdgcn_mfma_f32_16x16x32_bf16(af[tm], bf[tn], acc[tm][tn], 0, 0, 0);
    }
#pragma unroll
    for (int tm = 0; tm < 4; tm++)
#pragma unroll
        for (int tn = 0; tn < 4; tn++) {
            int row = m0 + wm + tm * 16 + lq * 4;
            int col = n0 + wn + tn * 16 + lm;
#pragma unroll
            for (int r = 0; r < 4; r++) {
                float v = acc[tm][tn][r];
                if constexpr (sizeof(OUT) == 2) C[(size_t)(row + r) * N + col] = (OUT)f2bf(v);
                else                            C[(size_t)(row + r) * N + col] = v;
            }
        }
}

// ---------------- build q_eff (scaled by 1/8) and k_eff per head ----------------
__global__ __launch_bounds__(256) void k_build(const unsigned short* __restrict__ qkv,
                                               const float* __restrict__ W_recip,
                                               const float* __restrict__ w_std,
                                               const float* __restrict__ w_rec,
                                               unsigned short* __restrict__ qe,
                                               unsigned short* __restrict__ ke) {
    __shared__ float Wr[64 * 8];
    int tid = threadIdx.x;
    for (int i = tid; i < 512; i += 256) Wr[i] = W_recip[i];
    __syncthreads();
    int g = blockIdx.x * 256 + tid;       // over B*H*T
    int t = g & (T_ - 1), h = (g >> 11) & (H_ - 1), b = g >> 15;
    float ws = sqrtf(fmaxf(w_std[h], 1e-8f));
    float wr = sqrtf(fmaxf(w_rec[h], 1e-8f));
    bool ra = w_rec[h] > 0.1f;
    const unsigned short* qrow = qkv + (size_t)(b * T_ + t) * 3072 + h * 64;
    const unsigned short* krow = qrow + 1024;
    float q[64], k[64];
#pragma unroll
    for (int i = 0; i < 8; i++) {
        short8 qv = *(const short8*)&qrow[i * 8];
        short8 kv = *(const short8*)&krow[i * 8];
#pragma unroll
        for (int j = 0; j < 8; j++) {
            q[i * 8 + j] = bf2f((unsigned short)qv[j]);
            k[i * 8 + j] = bf2f((unsigned short)kv[j]);
        }
    }
    float QW[8], KW[8];
#pragma unroll
    for (int r = 0; r < 8; r++) { QW[r] = 0.f; KW[r] = 0.f; }
#pragma unroll
    for (int d = 0; d < 64; d++)
#pragma unroll
        for (int r = 0; r < 8; r++) {
            QW[r] += q[d] * Wr[d * 8 + r];
            KW[r] += k[d] * Wr[d * 8 + r];
        }
    size_t obase = (size_t)((b * H_ + h) * T_ + t) * 64;
#pragma unroll
    for (int i = 0; i < 8; i++) {
        union { unsigned short u[8]; short8 s; } uq, uk;
#pragma unroll
        for (int j = 0; j < 8; j++) {
            int d = i * 8 + j;
            float qv, kv;
            if (ra && d >= 56) { qv = wr * KW[d - 56]; kv = wr * QW[d - 56]; }  // q_aug<-KW, k_aug<-QW
            else               { qv = ws * q[d];       kv = ws * k[d]; }
            uq.u[j] = f2bf(qv * 0.125f);   // fold softmax scale (exact pow2) into q_eff
            uk.u[j] = f2bf(kv);
        }
        *(short8*)&qe[obase + i * 8] = uq.s;
        *(short8*)&ke[obase + i * 8] = uk.s;
    }
}

// ---------------- transpose V to (B,H,D,T) ----------------
__global__ __launch_bounds__(256) void k_vtr(const unsigned short* __restrict__ qkv,
                                             unsigned short* __restrict__ vt) {
    int tid = threadIdx.x;
    int g = blockIdx.x;                    // B*H*(T/32)
    int tchunk = g & 63;
    int h = (g >> 6) & 15, b = g >> 10;
    int d = tid & 63, tg = tid >> 6;
    int t0 = tchunk * 32 + tg * 8;
    union { unsigned short u[8]; short8 s; } v;
#pragma unroll
    for (int i = 0; i < 8; i++)
        v.u[i] = qkv[(size_t)(b * T_ + t0 + i) * 3072 + 2048 + h * 64 + d];
    *(short8*)&vt[(size_t)((b * H_ + h) * D_ + d) * T_ + t0] = v.s;
}

// ---------------- flash attention: 64 q-rows/block, 4 waves x 16 rows ----------------
__global__ __launch_bounds__(256) void k_attn(const unsigned short* __restrict__ qe,
                                              const unsigned short* __restrict__ ke,
                                              const unsigned short* __restrict__ vt,
                                              const float* __restrict__ bias,
                                              unsigned short* __restrict__ obf) {
    __shared__ __align__(16) unsigned short Ks[64 * 64];
    __shared__ __align__(16) unsigned short Vs[64 * 64];  // (d, t_local)
    __shared__ __align__(16) unsigned short Ps[4][16 * 64];
    int qb = blockIdx.x, bh = blockIdx.y;
    int b = bh >> 4, h = bh & 15;
    int i0 = qb * 64;
    int tid = threadIdx.x, l = tid & 63, w = tid >> 6;
    int lm = l & 15, lq = l >> 4;
    const size_t hb = (size_t)bh * T_ * 64;

    int qrow = i0 + w * 16 + lm;
    short8 qf0 = *(const short8*)&qe[hb + (size_t)qrow * 64 + lq * 8];
    short8 qf1 = *(const short8*)&qe[hb + (size_t)qrow * 64 + 32 + lq * 8];

    floatx4 Oacc[4];
#pragma unroll
    for (int i = 0; i < 4; i++) Oacc[i] = {0.f, 0.f, 0.f, 0.f};
    float mo[4] = {-3e38f, -3e38f, -3e38f, -3e38f};
    float ll[4] = {0.f, 0.f, 0.f, 0.f};
    const float* biash = bias + h * T_;

    for (int j0 = 0; j0 <= i0; j0 += 64) {
        __syncthreads();
#pragma unroll
        for (int r = 0; r < 2; r++) {
            int ci = tid + r * 256;
            int row = ci >> 3, off = (ci & 7) * 8;
            *(short8*)&Ks[row * 64 + off] = *(const short8*)&ke[hb + (size_t)(j0 + row) * 64 + off];
            *(short8*)&Vs[row * 64 + off] = *(const short8*)&vt[hb + (size_t)row * T_ + j0 + off];
        }
        __syncthreads();

        float sv[4][4];
#pragma unroll
        for (int jt = 0; jt < 4; jt++) {
            short8 kf0 = *(short8*)&Ks[(jt * 16 + lm) * 64 + lq * 8];
            short8 kf1 = *(short8*)&Ks[(jt * 16 + lm) * 64 + 32 + lq * 8];
            floatx4 s = {0.f, 0.f, 0.f, 0.f};
            s = __builtin_amdgcn_mfma_f32_16x16x32_bf16(qf0, kf0, s, 0, 0, 0);
            s = __builtin_amdgcn_mfma_f32_16x16x32_bf16(qf1, kf1, s, 0, 0, 0);
            int jg = j0 + jt * 16 + lm;
            float bj = biash[jg];
#pragma unroll
            for (int r = 0; r < 4; r++) {
                int ig = i0 + w * 16 + lq * 4 + r;
                sv[jt][r] = (jg <= ig) ? (s[r] + bj) : -1e9f;
            }
        }
        float al[4];
#pragma unroll
        for (int r = 0; r < 4; r++) {
            float mx = fmaxf(fmaxf(sv[0][r], sv[1][r]), fmaxf(sv[2][r], sv[3][r]));
#pragma unroll
            for (int off = 8; off >= 1; off >>= 1) mx = fmaxf(mx, __shfl_xor(mx, off));
            float mn = fmaxf(mo[r], mx);
            al[r] = __expf(mo[r] - mn);
            mo[r] = mn;
            float rs = 0.f;
#pragma unroll
            for (int jt = 0; jt < 4; jt++) {
                float p = __expf(sv[jt][r] - mn);
                sv[jt][r] = p;
                rs += p;
            }
#pragma unroll
            for (int off = 8; off >= 1; off >>= 1) rs += __shfl_xor(rs, off);
            ll[r] = ll[r] * al[r] + rs;
        }
#pragma unroll
        for (int dt = 0; dt < 4; dt++) {
            floatx4 o = Oacc[dt];
            o[0] *= al[0]; o[1] *= al[1]; o[2] *= al[2]; o[3] *= al[3];
            Oacc[dt] = o;
        }
#pragma unroll
        for (int jt = 0; jt < 4; jt++)
#pragma unroll
            for (int r = 0; r < 4; r++)
                Ps[w][(lq * 4 + r) * 64 + jt * 16 + lm] = f2bf(sv[jt][r]);
        __syncthreads();
        short8 pf0 = *(short8*)&Ps[w][lm * 64 + lq * 8];
        short8 pf1 = *(short8*)&Ps[w][lm * 64 + 32 + lq * 8];
#pragma unroll
        for (int dt = 0; dt < 4; dt++) {
            short8 vf0 = *(short8*)&Vs[(dt * 16 + lm) * 64 + lq * 8];
            short8 vf1 = *(short8*)&Vs[(dt * 16 + lm) * 64 + 32 + lq * 8];
            Oacc[dt] = __builtin_amdgcn_mfma_f32_16x16x32_bf16(pf0, vf0, Oacc[dt], 0, 0, 0);
            Oacc[dt] = __builtin_amdgcn_mfma_f32_16x16x32_bf16(pf1, vf1, Oacc[dt], 0, 0, 0);
        }
    }
    int tglob = i0 + w * 16 + lq * 4;
#pragma unroll
    for (int dt = 0; dt < 4; dt++) {
        float inv[4];
#pragma unroll
        for (int r = 0; r < 4; r++) {
            float v = Oacc[dt][r] / ll[r];
            obf[(size_t)(b * T_ + tglob + r) * C_ + h * 64 + dt * 16 + lm] = f2bf(v);
        }
        (void)inv;
    }
}

extern "C" void kernel_launch(void* const* d_in, const int* in_sizes, int n_in,
                              void* d_out, int out_size, void* d_ws, size_t ws_size,
                              hipStream_t stream) {
    const float* x       = (const float*)d_in[0];
    const float* W_attn  = (const float*)d_in[1];
    const float* W_proj  = (const float*)d_in[2];
    const float* W_recip = (const float*)d_in[3];
    const float* w_std   = (const float*)d_in[4];
    const float* w_rec   = (const float*)d_in[5];
    const float* w_disc  = (const float*)d_in[6];
    const float* d_bias  = (const float*)d_in[7];

    char* ws = (char*)d_ws;
    size_t o = 0;
    unsigned short* x_bf = (unsigned short*)(ws + o); o += (size_t)4096 * 1024 * 2;  // 8 MB
    unsigned short* wa_t = (unsigned short*)(ws + o); o += (size_t)3072 * 1024 * 2;  // 6 MB
    unsigned short* wp_t = (unsigned short*)(ws + o); o += (size_t)1024 * 1024 * 2;  // 2 MB
    unsigned short* qkv  = (unsigned short*)(ws + o); o += (size_t)4096 * 3072 * 2;  // 24 MB
    unsigned short* qe   = (unsigned short*)(ws + o); o += (size_t)32 * 2048 * 64 * 2;
    unsigned short* ke   = (unsigned short*)(ws + o); o += (size_t)32 * 2048 * 64 * 2;
    unsigned short* vt   = (unsigned short*)(ws + o); o += (size_t)32 * 2048 * 64 * 2;
    unsigned short* obf  = (unsigned short*)(ws + o); o += (size_t)4096 * 1024 * 2;
    float* bias          = (float*)(ws + o);          o += (size_t)16 * 2048 * 4;

    k_cvt<<<2048, 256, 0, stream>>>(x, x_bf, 524288);
    k_tr<<<dim3(48, 16), 256, 0, stream>>>(W_attn, wa_t, 1024, 3072);
    k_tr<<<dim3(16, 16), 256, 0, stream>>>(W_proj, wp_t, 1024, 1024);
    k_bias<<<16, 256, 0, stream>>>(d_bias, w_disc, bias);
    k_gemm<unsigned short><<<dim3(24, 32), 256, 0, stream>>>(x_bf, wa_t, qkv, 4096, 3072, 1024);
    k_build<<<256, 256, 0, stream>>>(qkv, W_recip, w_std, w_rec, qe, ke);
    k_vtr<<<2048, 256, 0, stream>>>(qkv, vt);
    k_attn<<<dim3(32, 32), 256, 0, stream>>>(qe, ke, vt, bias, obf);
    k_gemm<float><<<dim3(8, 32), 256, 0, stream>>>(obf, wp_t, (float*)d_out, 4096, 1024, 1024);
}